// Round 1
// baseline (938.816 us; speedup 1.0000x reference)
//
#include <hip/hip_runtime.h>

// Problem constants (from reference)
constexpr int B = 1024, C = 20, N = 26, VDIM = 128, NSPL = 10, NWORDS = 100000;
constexpr int SCORE_BLOCKS = B;          // one block per batch row
constexpr int COPY_BLOCKS  = 3072;       // grid-stride float4 copy of D
constexpr size_t D_ELEMS = (size_t)NSPL * NWORDS * VDIM;   // 128,000,000 floats
constexpr size_t D_F4    = D_ELEMS / 4;                    // 32,000,000 float4
constexpr size_t SCORES_ELEMS = (size_t)B * N;             // 26,624 floats (16B-aligned)

typedef float f4 __attribute__((ext_vector_type(4)));

__global__ __launch_bounds__(256) void dmspline_fused(
    const float* __restrict__ x_vals,       // (B,)
    const int*   __restrict__ knot_ids,     // (B,)
    const int*   __restrict__ context_ids,  // (B, C)
    const int*   __restrict__ tgt_ids,      // (B, N)
    const float* __restrict__ D,            // (NSPL, NWORDS, VDIM)
    const float* __restrict__ W,            // (NWORDS, VDIM)
    const float* __restrict__ O,            // (VDIM, NWORDS)
    float*       __restrict__ out)          // scores (B*N) ++ D (D_ELEMS)
{
    const int bid = blockIdx.x;
    const int tid = threadIdx.x;

    if (bid >= SCORE_BLOCKS) {
        // ---- D -> out copy: streaming, non-temporal (don't evict O/W from L2/L3) ----
        const f4* __restrict__ src = (const f4*)D;
        f4* __restrict__ dst = (f4*)(out + SCORES_ELEMS);
        size_t i = (size_t)(bid - SCORE_BLOCKS) * 256 + tid;
        const size_t stride = (size_t)COPY_BLOCKS * 256;

        // 4x unrolled: 4 nt loads in flight, then 4 nt stores
        while (i + 3 * stride < D_F4) {
            f4 a0 = __builtin_nontemporal_load(src + i);
            f4 a1 = __builtin_nontemporal_load(src + i + stride);
            f4 a2 = __builtin_nontemporal_load(src + i + 2 * stride);
            f4 a3 = __builtin_nontemporal_load(src + i + 3 * stride);
            __builtin_nontemporal_store(a0, dst + i);
            __builtin_nontemporal_store(a1, dst + i + stride);
            __builtin_nontemporal_store(a2, dst + i + 2 * stride);
            __builtin_nontemporal_store(a3, dst + i + 3 * stride);
            i += 4 * stride;
        }
        for (; i < D_F4; i += stride) {
            f4 a = __builtin_nontemporal_load(src + i);
            __builtin_nontemporal_store(a, dst + i);
        }
        return;
    }

    // ---- scores path: one block per b ----
    __shared__ float sh_part[256];
    const int b = bid;

    {
        // all 256 threads: thread (half, v) accumulates c in [half*10, half*10+10)
        const int v    = tid & 127;
        const int half = tid >> 7;
        const float xv   = x_vals[b];
        const int   knot = knot_ids[b];
        const float* __restrict__ Dk = D + (size_t)knot * NWORDS * VDIM + v;
        const float* __restrict__ Wv = W + v;

        // prefetch the 10 context ids first (independent loads)
        int ctx[10];
        #pragma unroll
        for (int c = 0; c < 10; ++c)
            ctx[c] = context_ids[b * C + half * 10 + c];

        float acc = 0.f;
        #pragma unroll
        for (int c = 0; c < 10; ++c)
            acc += Dk[(size_t)ctx[c] * VDIM] * xv + Wv[(size_t)ctx[c] * VDIM];
        sh_part[tid] = acc;
    }
    __syncthreads();

    const int wave = tid >> 6;
    const int lane = tid & 63;
    constexpr float invC = 1.0f / C;
    const float x0 = (sh_part[lane]      + sh_part[lane + 128]) * invC;
    const float x1 = (sh_part[lane + 64] + sh_part[lane + 192]) * invC;
    const float* __restrict__ O0 = O + (size_t)lane * NWORDS;
    const float* __restrict__ O1 = O + (size_t)(lane + 64) * NWORDS;

    // 4 waves split N=26 targets round-robin; batch all loads to overlap latency.
    // All indices compile-time (full unroll) so arrays stay in registers.
    int ids[7];
    #pragma unroll
    for (int k = 0; k < 7; ++k) {
        const int n = wave + 4 * k;
        ids[k] = (n < N) ? tgt_ids[b * N + n] : tgt_ids[b * N];  // safe dummy
    }
    float p0[7], p1[7];
    #pragma unroll
    for (int k = 0; k < 7; ++k) {
        p0[k] = O0[ids[k]];
        p1[k] = O1[ids[k]];
    }
    #pragma unroll
    for (int k = 0; k < 7; ++k) {
        const int n = wave + 4 * k;   // wave-uniform condition, no divergence
        if (n < N) {
            float p = x0 * p0[k] + x1 * p1[k];
            #pragma unroll
            for (int m = 32; m >= 1; m >>= 1)
                p += __shfl_xor(p, m, 64);
            if (lane == 0)
                out[(size_t)b * N + n] = p;
        }
    }
}

extern "C" void kernel_launch(void* const* d_in, const int* in_sizes, int n_in,
                              void* d_out, int out_size, void* d_ws, size_t ws_size,
                              hipStream_t stream) {
    const float* x_vals      = (const float*)d_in[0];
    const int*   knot_ids    = (const int*)  d_in[1];
    const int*   context_ids = (const int*)  d_in[2];
    const int*   tgt_ids     = (const int*)  d_in[3];
    const float* D           = (const float*)d_in[4];
    const float* W           = (const float*)d_in[5];
    const float* O           = (const float*)d_in[6];
    float*       out         = (float*)d_out;

    dim3 grid(SCORE_BLOCKS + COPY_BLOCKS);
    dim3 block(256);
    dmspline_fused<<<grid, block, 0, stream>>>(x_vals, knot_ids, context_ids,
                                               tgt_ids, D, W, O, out);
}

// Round 2
// 918.743 us; speedup vs baseline: 1.0218x; 1.0218x over previous
//
#include <hip/hip_runtime.h>

// Problem constants (from reference)
constexpr int B = 1024, C = 20, N = 26, VDIM = 128, NSPL = 10, NWORDS = 100000;
constexpr size_t D_ELEMS = (size_t)NSPL * NWORDS * VDIM;   // 128,000,000 floats
constexpr size_t SCORES_ELEMS = (size_t)B * N;             // 26,624 floats (16B-aligned)

__global__ __launch_bounds__(256) void dmspline_scores(
    const float* __restrict__ x_vals,       // (B,)
    const int*   __restrict__ knot_ids,     // (B,)
    const int*   __restrict__ context_ids,  // (B, C)
    const int*   __restrict__ tgt_ids,      // (B, N)
    const float* __restrict__ D,            // (NSPL, NWORDS, VDIM)
    const float* __restrict__ W,            // (NWORDS, VDIM)
    const float* __restrict__ O,            // (VDIM, NWORDS)
    float*       __restrict__ out)          // scores (B*N)
{
    const int b   = blockIdx.x;
    const int tid = threadIdx.x;

    __shared__ float sh_part[256];

    {
        // all 256 threads: thread (half, v) accumulates c in [half*10, half*10+10)
        const int v    = tid & 127;
        const int half = tid >> 7;
        const float xv   = x_vals[b];
        const int   knot = knot_ids[b];
        const float* __restrict__ Dk = D + (size_t)knot * NWORDS * VDIM + v;
        const float* __restrict__ Wv = W + v;

        // prefetch the 10 context ids first (independent loads)
        int ctx[10];
        #pragma unroll
        for (int c = 0; c < 10; ++c)
            ctx[c] = context_ids[b * C + half * 10 + c];

        float acc = 0.f;
        #pragma unroll
        for (int c = 0; c < 10; ++c)
            acc += Dk[(size_t)ctx[c] * VDIM] * xv + Wv[(size_t)ctx[c] * VDIM];
        sh_part[tid] = acc;
    }
    __syncthreads();

    const int wave = tid >> 6;
    const int lane = tid & 63;
    constexpr float invC = 1.0f / C;
    const float x0 = (sh_part[lane]      + sh_part[lane + 128]) * invC;
    const float x1 = (sh_part[lane + 64] + sh_part[lane + 192]) * invC;
    const float* __restrict__ O0 = O + (size_t)lane * NWORDS;
    const float* __restrict__ O1 = O + (size_t)(lane + 64) * NWORDS;

    // 4 waves split N=26 targets round-robin; batch all loads to overlap latency.
    // All indices compile-time (full unroll) so arrays stay in registers.
    int ids[7];
    #pragma unroll
    for (int k = 0; k < 7; ++k) {
        const int n = wave + 4 * k;
        ids[k] = (n < N) ? tgt_ids[b * N + n] : tgt_ids[b * N];  // safe dummy
    }
    float p0[7], p1[7];
    #pragma unroll
    for (int k = 0; k < 7; ++k) {
        p0[k] = O0[ids[k]];
        p1[k] = O1[ids[k]];
    }
    #pragma unroll
    for (int k = 0; k < 7; ++k) {
        const int n = wave + 4 * k;   // wave-uniform condition, no divergence
        if (n < N) {
            float p = x0 * p0[k] + x1 * p1[k];
            #pragma unroll
            for (int m = 32; m >= 1; m >>= 1)
                p += __shfl_xor(p, m, 64);
            if (lane == 0)
                out[(size_t)b * N + n] = p;
        }
    }
}

extern "C" void kernel_launch(void* const* d_in, const int* in_sizes, int n_in,
                              void* d_out, int out_size, void* d_ws, size_t ws_size,
                              hipStream_t stream) {
    const float* x_vals      = (const float*)d_in[0];
    const int*   knot_ids    = (const int*)  d_in[1];
    const int*   context_ids = (const int*)  d_in[2];
    const int*   tgt_ids     = (const int*)  d_in[3];
    const float* D           = (const float*)d_in[4];
    const float* W           = (const float*)d_in[5];
    const float* O           = (const float*)d_in[6];
    float*       out         = (float*)d_out;

    // Scores: small latency-bound kernel (one block per batch row).
    dmspline_scores<<<dim3(B), dim3(256), 0, stream>>>(
        x_vals, knot_ids, context_ids, tgt_ids, D, W, O, out);

    // D passthrough: let the runtime's tuned blit kernel move 512 MB at
    // full HBM rate (fills on this chip sustain ~6.35 TB/s).
    hipMemcpyAsync(out + SCORES_ELEMS, D, D_ELEMS * sizeof(float),
                   hipMemcpyDeviceToDevice, stream);
}